// Round 4
// baseline (451.747 us; speedup 1.0000x reference)
//
#include <hip/hip_runtime.h>
#include <hip/hip_bf16.h>
#include <math.h>

typedef __attribute__((ext_vector_type(8))) short bf16x8;
typedef __attribute__((ext_vector_type(4))) float f32x4;
typedef __attribute__((ext_vector_type(16))) float f32x16;

__device__ __forceinline__ ushort f2bf(float f) {
  union { float f; unsigned u; } v; v.f = f;
  unsigned u = v.u + 0x7FFFu + ((v.u >> 16) & 1u);
  return (ushort)(u >> 16);
}
__device__ __forceinline__ float bf2f(ushort h) {
  union { unsigned u; float f; } v; v.u = ((unsigned)h) << 16;
  return v.f;
}
__device__ __forceinline__ unsigned pk2bf(float a, float b) {
  __hip_bfloat162 h = __float22bfloat162_rn(float2{a, b});
  union { __hip_bfloat162 h; unsigned u; } cv; cv.h = h; return cv.u;
}
__device__ __forceinline__ void gload_lds16(const ushort* g, ushort* l) {
  __builtin_amdgcn_global_load_lds((const __attribute__((address_space(1))) void*)g,
                                   (__attribute__((address_space(3))) void*)l, 16, 0, 0);
}

// ---------------------------------------------------------------- prep: casts + packing
__global__ __launch_bounds__(256) void prep_kernel(
    const float* __restrict__ hs, const float* __restrict__ qw,
    const float* __restrict__ kw, const float* __restrict__ vw,
    const float* __restrict__ ow, const float* __restrict__ qb,
    const float* __restrict__ kb, const float* __restrict__ vb,
    ushort* __restrict__ hs_b, ushort* __restrict__ qkvw_b,
    ushort* __restrict__ ow_b, float* __restrict__ qkvb)
{
  const int idx = blockIdx.x * 256 + threadIdx.x;
  const int stride = gridDim.x * 256;
  const float4* hs4 = (const float4*)hs;
  const float4* qw4 = (const float4*)qw;
  const float4* kw4 = (const float4*)kw;
  const float4* vw4 = (const float4*)vw;
  const float4* ow4 = (const float4*)ow;
  ushort4* hsb4 = (ushort4*)hs_b;
  ushort4* qkvwb4 = (ushort4*)qkvw_b;
  ushort4* owb4 = (ushort4*)ow_b;

  for (int i = idx; i < 2097152; i += stride) {
    float4 v = hs4[i];
    ushort4 o; o.x=f2bf(v.x); o.y=f2bf(v.y); o.z=f2bf(v.z); o.w=f2bf(v.w);
    hsb4[i] = o;
  }
  for (int i = idx; i < 1048576; i += stride) {
    float4 v = qw4[i];
    ushort4 o; o.x=f2bf(v.x); o.y=f2bf(v.y); o.z=f2bf(v.z); o.w=f2bf(v.w);
    qkvwb4[i] = o;
  }
  for (int i = idx; i < 262144; i += stride) {
    float4 v = kw4[i];
    ushort4 o; o.x=f2bf(v.x); o.y=f2bf(v.y); o.z=f2bf(v.z); o.w=f2bf(v.w);
    qkvwb4[1048576 + i] = o;
  }
  for (int i = idx; i < 262144; i += stride) {
    float4 v = vw4[i];
    ushort4 o; o.x=f2bf(v.x); o.y=f2bf(v.y); o.z=f2bf(v.z); o.w=f2bf(v.w);
    qkvwb4[1310720 + i] = o;
  }
  for (int i = idx; i < 1048576; i += stride) {
    float4 v = ow4[i];
    ushort4 o; o.x=f2bf(v.x); o.y=f2bf(v.y); o.z=f2bf(v.z); o.w=f2bf(v.w);
    owb4[i] = o;
  }
  for (int i = idx; i < 3072; i += stride)
    qkvb[i] = (i < 2048) ? qb[i] : (i < 2560 ? kb[i - 2048] : vb[i - 2560]);
}

// ---------------------------------------------------------------- GEMM: C = A(MxK) * Bw(NxK)^T + bias
template<int BF16OUT>
__global__ __launch_bounds__(256) void gemm_bt(
    const ushort* __restrict__ A, const ushort* __restrict__ Bw,
    const float* __restrict__ bias, void* __restrict__ Cout,
    ushort* __restrict__ vt,
    int M, int N, int K, int ldc, int vsplit)
{
  __shared__ ushort As[128 * 32];
  __shared__ ushort Bs[128 * 32];
  const int t = threadIdx.x;
  const int wv = t >> 6;
  const int lane = t & 63;
  const int qd = lane >> 4, ln = lane & 15;
  const long row0 = (long)blockIdx.x * 128, col0 = (long)blockIdx.y * 128;
  const int wm = (wv >> 1) * 64, wn = (wv & 1) * 64;

  f32x4 acc[4][4];
#pragma unroll
  for (int i = 0; i < 4; i++)
#pragma unroll
    for (int j = 0; j < 4; j++) acc[i][j] = (f32x4){0.f, 0.f, 0.f, 0.f};

  const ushort* gA = A + (row0 + (t >> 2)) * (long)K + (t & 3) * 8;
  const ushort* gB = Bw + (col0 + (t >> 2)) * (long)K + (t & 3) * 8;
  ushort* lA = &As[wv * 512];
  ushort* lB = &Bs[wv * 512];
  const long K64 = 64l * K;

  for (int kt = 0; kt < K; kt += 32) {
    __syncthreads();
    gload_lds16(gA + kt,        lA);
    gload_lds16(gA + kt + K64,  lA + 2048);
    gload_lds16(gB + kt,        lB);
    gload_lds16(gB + kt + K64,  lB + 2048);
    __syncthreads();
    bf16x8 af[4], bf[4];
#pragma unroll
    for (int mi = 0; mi < 4; mi++)
      af[mi] = *(const bf16x8*)&As[(wm + mi * 16 + ln) * 32 + qd * 8];
#pragma unroll
    for (int ni = 0; ni < 4; ni++)
      bf[ni] = *(const bf16x8*)&Bs[(wn + ni * 16 + ln) * 32 + qd * 8];
#pragma unroll
    for (int mi = 0; mi < 4; mi++)
#pragma unroll
      for (int ni = 0; ni < 4; ni++)
        acc[mi][ni] = __builtin_amdgcn_mfma_f32_16x16x32_bf16(af[mi], bf[ni], acc[mi][ni], 0, 0, 0);
  }

  float bv[4];
#pragma unroll
  for (int ni = 0; ni < 4; ni++) bv[ni] = bias[col0 + wn + ni * 16 + ln];

  if (col0 >= vsplit) {
#pragma unroll
    for (int mi = 0; mi < 4; mi++)
#pragma unroll
      for (int ni = 0; ni < 4; ni++)
#pragma unroll
        for (int r = 0; r < 4; r++) {
          long row = row0 + wm + mi * 16 + qd * 4 + r;
          long col = col0 + wn + ni * 16 + ln - vsplit;
          vt[col * 4096 + row] = f2bf(acc[mi][ni][r] + bv[ni]);
        }
  } else {
#pragma unroll
    for (int mi = 0; mi < 4; mi++)
#pragma unroll
      for (int ni = 0; ni < 4; ni++)
#pragma unroll
        for (int r = 0; r < 4; r++) {
          long row = row0 + wm + mi * 16 + qd * 4 + r;
          long col = col0 + wn + ni * 16 + ln;
          float v = acc[mi][ni][r] + bv[ni];
          if (BF16OUT) ((ushort*)Cout)[row * ldc + col] = f2bf(v);
          else         ((float*)Cout)[row * ldc + col] = v;
        }
  }
}

// ---------------------------------------------------------------- RoPE in place on Q/K (qk buffer, ld=2560)
__global__ __launch_bounds__(256) void rope_kernel(ushort* __restrict__ qk)
{
  const int i = blockIdx.x * 256 + threadIdx.x;
  if (i >= 5242880) return;
  const int pair = i & 63;
  const int head = (i >> 6) % 20;
  const int row  = (i >> 6) / 20;
  const int pos  = row & 2047;
  const int base = head < 16 ? head * 128 : 2048 + (head - 16) * 128;
  ushort* p = qk + (long)row * 2560 + base + pair;
  const float v0 = bf2f(p[0]);
  const float v1 = bf2f(p[64]);
  const float inv = expf((float)pair * -0.14391156831212787f);
  const float ang = (float)pos * inv;
  const float sc = (head < 16) ? 0.08838834764831845f : 1.0f;  // fold 1/sqrt(d) into Q
  const float c = cosf(ang) * sc, s = sinf(ang) * sc;
  p[0]  = f2bf(v0 * c - v1 * s);
  p[64] = f2bf(v1 * c + v0 * s);
}

// ---------------------------------------------------------------- flash attention v4
// v3 transposed structure (S^T = K·Q^T, O^T = V^T·P^T, 32x32x16 MFMA, m=0 softmax),
// restructured for register liveness: kpos-block-phased softmax+PV so only 16 sacc regs
// and one 4-reg P-frag are live at a time (v3 spilled ~270 MB/launch to scratch).
__global__ __launch_bounds__(256, 2) void flash_kernel(
    const ushort* __restrict__ qk, const ushort* __restrict__ vt,
    ushort* __restrict__ ctx)
{
  __shared__ ushort smem[17920];          // Ks [64][136] @0 (8704) + Vts [128][72] @8704 (9216)
  ushort* Ks  = smem;                     // reused as O-transpose buffer [128][136] at the end
  ushort* Vts = smem + 8704;

  const int t = threadIdx.x, lane = t & 63, wv = t >> 6;
  const int h2 = lane >> 5, m = lane & 31;
  const int q0 = blockIdx.x * 128;
  const int b = blockIdx.y >> 4, h = blockIdx.y & 15;
  const long rb = (long)b * 2048;
  const ushort* Qg  = qk + (rb + q0) * 2560 + h * 128;
  const ushort* Kg  = qk + rb * 2560 + 2048 + (h >> 2) * 128;
  const ushort* Vtg = vt + ((long)(h >> 2) * 128) * 4096 + rb;

  // Q B-frags in registers: lane (h2, m) holds Q[q = wv*32+m][d = 16*s2 + 8*h2 + 0..7]
  bf16x8 qf[8];
  {
    const ushort* qrow = Qg + (long)(wv * 32 + m) * 2560 + h2 * 8;
#pragma unroll
    for (int s2 = 0; s2 < 8; s2++)
      qf[s2] = *(const bf16x8*)(qrow + s2 * 16);
  }

  f32x16 oacc[4];
#pragma unroll
  for (int d = 0; d < 4; d++)
#pragma unroll
    for (int r = 0; r < 16; r++) oacc[d][r] = 0.f;
  float l_run = 0.f;

  const int sr  = t >> 4;          // 0..15 (K rows)
  const int sc8 = (t & 15) * 8;
  const int vd  = t >> 1;          // 0..127 (V d-rows)
  const int vc  = (t & 1) * 4;

  // prefetch tile kt=0
  uint4 kreg[4], vreg[4];
#pragma unroll
  for (int i = 0; i < 4; i++)
    kreg[i] = *(const uint4*)(Kg + (long)(16 * i + sr) * 2560 + sc8);
#pragma unroll
  for (int c = 0; c < 4; c++)
    vreg[c] = *(const uint4*)(Vtg + (long)vd * 4096 + (vc + c) * 8);

  for (int kt = 0; kt < 2048; kt += 64) {
    __syncthreads();                       // previous iter's LDS reads done
#pragma unroll
    for (int i = 0; i < 4; i++)
      *(uint4*)&Ks[(16 * i + sr) * 136 + sc8] = kreg[i];
#pragma unroll
    for (int c = 0; c < 4; c++)
      *(uint4*)&Vts[vd * 72 + (vc + c) * 8] = vreg[c];
    {
      int ktn = (kt + 64) & 2047;          // next tile loads stay in flight across compute
#pragma unroll
      for (int i = 0; i < 4; i++)
        kreg[i] = *(const uint4*)(Kg + (long)(ktn + 16 * i + sr) * 2560 + sc8);
#pragma unroll
      for (int c = 0; c < 4; c++)
        vreg[c] = *(const uint4*)(Vtg + (long)vd * 4096 + ktn + (vc + c) * 8);
    }
    __syncthreads();

    float s_sum = 0.f;
#pragma unroll
    for (int kb = 0; kb < 2; kb++) {
      // S^T[kpos-block kb][q-block wv] = K·Q^T  (16 live sacc regs)
      f32x16 sacc;
#pragma unroll
      for (int r = 0; r < 16; r++) sacc[r] = 0.f;
#pragma unroll
      for (int s2 = 0; s2 < 8; s2++) {
        bf16x8 kf = *(const bf16x8*)&Ks[(32 * kb + m) * 136 + s2 * 16 + h2 * 8];
        sacc = __builtin_amdgcn_mfma_f32_32x32x16_bf16(kf, qf[s2], sacc, 0, 0, 0);
      }
      // softmax (m=0) + build P^T B-frag + PV, one 16-k step at a time
#pragma unroll
      for (int sh = 0; sh < 2; sh++) {
        float e[8];
#pragma unroll
        for (int j = 0; j < 8; j++) {
          e[j] = __expf(sacc[8 * sh + j]);
          s_sum += e[j];
        }
        unsigned u0 = pk2bf(e[0], e[1]);
        unsigned u1 = pk2bf(e[2], e[3]);
        unsigned u2 = pk2bf(e[4], e[5]);
        unsigned u3 = pk2bf(e[6], e[7]);
        unsigned u0s = (unsigned)__shfl_xor((int)u0, 32, 64);
        unsigned u1s = (unsigned)__shfl_xor((int)u1, 32, 64);
        unsigned u2s = (unsigned)__shfl_xor((int)u2, 32, 64);
        unsigned u3s = (unsigned)__shfl_xor((int)u3, 32, 64);
        union { unsigned u[4]; bf16x8 v; } pf;
        pf.u[0] = h2 ? u2s : u0;
        pf.u[1] = h2 ? u3s : u1;
        pf.u[2] = h2 ? u2 : u0s;
        pf.u[3] = h2 ? u3 : u1s;
        const int s = 2 * kb + sh;
#pragma unroll
        for (int db = 0; db < 4; db++) {
          bf16x8 vf = *(const bf16x8*)&Vts[(db * 32 + m) * 72 + s * 16 + h2 * 8];
          oacc[db] = __builtin_amdgcn_mfma_f32_32x32x16_bf16(vf, pf.v, oacc[db], 0, 0, 0);
        }
      }
    }
    l_run += s_sum + __int_as_float(__shfl_xor(__float_as_int(s_sum), 32, 64));
  }

  // epilogue: O^T/l -> LDS transpose -> coalesced ctx stores
  const float linv = 1.f / (l_run + 1e-10f);
  __syncthreads();                          // all waves done reading Ks/Vts
  ushort* Obuf = smem;                      // [128 q][136]
#pragma unroll
  for (int db = 0; db < 4; db++)
#pragma unroll
    for (int r = 0; r < 16; r++) {
      int d = db * 32 + (r & 3) + 8 * (r >> 2) + 4 * h2;
      Obuf[(wv * 32 + m) * 136 + d] = f2bf(oacc[db][r] * linv);
    }
  __syncthreads();
  {
    int qr = t >> 1;
    ushort* dst = ctx + (rb + q0 + qr) * 2048 + h * 128;
#pragma unroll
    for (int c = 0; c < 8; c++) {
      int off = ((t & 1) * 8 + c) * 8;
      *(uint4*)(dst + off) = *(const uint4*)&Obuf[qr * 136 + off];
    }
  }
}

// ---------------------------------------------------------------- launch
extern "C" void kernel_launch(void* const* d_in, const int* in_sizes, int n_in,
                              void* d_out, int out_size, void* d_ws, size_t ws_size,
                              hipStream_t stream)
{
  const float* hs = (const float*)d_in[0];
  const float* qw = (const float*)d_in[1];
  const float* qb = (const float*)d_in[2];
  const float* kw = (const float*)d_in[3];
  const float* kb = (const float*)d_in[4];
  const float* vw = (const float*)d_in[5];
  const float* vb = (const float*)d_in[6];
  const float* ow = (const float*)d_in[7];
  const float* ob = (const float*)d_in[8];

  char* ws = (char*)d_ws;
  ushort* hs_b   = (ushort*)(ws);                 // 16,777,216 B
  ushort* qkvw_b = (ushort*)(ws + 16777216);      // 12,582,912 B
  ushort* ow_b   = (ushort*)(ws + 29360128);      //  8,388,608 B
  float*  qkvb   = (float*) (ws + 37748736);      //     12,288 B
  ushort* qkbuf  = (ushort*)(ws + 37761024);      // 20,971,520 B  [4096][2560]
  ushort* vtbuf  = (ushort*)(ws + 58732544);      //  4,194,304 B  [512][4096]
  ushort* ctx    = (ushort*)(ws + 62926848);      // 16,777,216 B

  prep_kernel<<<1024, 256, 0, stream>>>(hs, qw, kw, vw, ow, qb, kb, vb,
                                        hs_b, qkvw_b, ow_b, qkvb);
  gemm_bt<1><<<dim3(32, 24), 256, 0, stream>>>(hs_b, qkvw_b, qkvb, qkbuf, vtbuf,
                                               4096, 3072, 2048, 2560, 2560);
  rope_kernel<<<20480, 256, 0, stream>>>(qkbuf);
  flash_kernel<<<dim3(16, 32), 256, 0, stream>>>(qkbuf, vtbuf, ctx);
  gemm_bt<0><<<dim3(32, 16), 256, 0, stream>>>(ctx, ow_b, ob, d_out, nullptr,
                                               4096, 2048, 2048, 2048, 1 << 30);
}

// Round 5
// 450.361 us; speedup vs baseline: 1.0031x; 1.0031x over previous
//
#include <hip/hip_runtime.h>
#include <hip/hip_bf16.h>
#include <math.h>

typedef __attribute__((ext_vector_type(8))) short bf16x8;
typedef __attribute__((ext_vector_type(4))) float f32x4;
typedef __attribute__((ext_vector_type(16))) float f32x16;
typedef __attribute__((ext_vector_type(4))) unsigned int u32x4;

__device__ __forceinline__ ushort f2bf(float f) {
  unsigned u = __float_as_uint(f);
  u = u + 0x7FFFu + ((u >> 16) & 1u);
  return (ushort)(u >> 16);
}
__device__ __forceinline__ float bf2f(ushort h) {
  return __uint_as_float(((unsigned)h) << 16);
}
// pack two floats to bf16x2 (RNE), pure integer ops — no struct/union (keeps SROA happy)
__device__ __forceinline__ unsigned pk2bf(float a, float b) {
  unsigned ua = __float_as_uint(a);
  unsigned ub = __float_as_uint(b);
  ua = ua + 0x7FFFu + ((ua >> 16) & 1u);
  ub = ub + 0x7FFFu + ((ub >> 16) & 1u);
  return (ua >> 16) | (ub & 0xFFFF0000u);
}
__device__ __forceinline__ void gload_lds16(const ushort* g, ushort* l) {
  __builtin_amdgcn_global_load_lds((const __attribute__((address_space(1))) void*)g,
                                   (__attribute__((address_space(3))) void*)l, 16, 0, 0);
}

// ---------------------------------------------------------------- prep: casts + packing
__global__ __launch_bounds__(256) void prep_kernel(
    const float* __restrict__ hs, const float* __restrict__ qw,
    const float* __restrict__ kw, const float* __restrict__ vw,
    const float* __restrict__ ow, const float* __restrict__ qb,
    const float* __restrict__ kb, const float* __restrict__ vb,
    ushort* __restrict__ hs_b, ushort* __restrict__ qkvw_b,
    ushort* __restrict__ ow_b, float* __restrict__ qkvb)
{
  const int idx = blockIdx.x * 256 + threadIdx.x;
  const int stride = gridDim.x * 256;
  const float4* hs4 = (const float4*)hs;
  const float4* qw4 = (const float4*)qw;
  const float4* kw4 = (const float4*)kw;
  const float4* vw4 = (const float4*)vw;
  const float4* ow4 = (const float4*)ow;
  ushort4* hsb4 = (ushort4*)hs_b;
  ushort4* qkvwb4 = (ushort4*)qkvw_b;
  ushort4* owb4 = (ushort4*)ow_b;

  for (int i = idx; i < 2097152; i += stride) {
    float4 v = hs4[i];
    ushort4 o; o.x=f2bf(v.x); o.y=f2bf(v.y); o.z=f2bf(v.z); o.w=f2bf(v.w);
    hsb4[i] = o;
  }
  for (int i = idx; i < 1048576; i += stride) {
    float4 v = qw4[i];
    ushort4 o; o.x=f2bf(v.x); o.y=f2bf(v.y); o.z=f2bf(v.z); o.w=f2bf(v.w);
    qkvwb4[i] = o;
  }
  for (int i = idx; i < 262144; i += stride) {
    float4 v = kw4[i];
    ushort4 o; o.x=f2bf(v.x); o.y=f2bf(v.y); o.z=f2bf(v.z); o.w=f2bf(v.w);
    qkvwb4[1048576 + i] = o;
  }
  for (int i = idx; i < 262144; i += stride) {
    float4 v = vw4[i];
    ushort4 o; o.x=f2bf(v.x); o.y=f2bf(v.y); o.z=f2bf(v.z); o.w=f2bf(v.w);
    qkvwb4[1310720 + i] = o;
  }
  for (int i = idx; i < 1048576; i += stride) {
    float4 v = ow4[i];
    ushort4 o; o.x=f2bf(v.x); o.y=f2bf(v.y); o.z=f2bf(v.z); o.w=f2bf(v.w);
    owb4[i] = o;
  }
  for (int i = idx; i < 3072; i += stride)
    qkvb[i] = (i < 2048) ? qb[i] : (i < 2560 ? kb[i - 2048] : vb[i - 2560]);
}

// ---------------------------------------------------------------- GEMM: C = A(MxK) * Bw(NxK)^T + bias
template<int BF16OUT>
__global__ __launch_bounds__(256) void gemm_bt(
    const ushort* __restrict__ A, const ushort* __restrict__ Bw,
    const float* __restrict__ bias, void* __restrict__ Cout,
    ushort* __restrict__ vt,
    int M, int N, int K, int ldc, int vsplit)
{
  __shared__ ushort As[128 * 32];
  __shared__ ushort Bs[128 * 32];
  const int t = threadIdx.x;
  const int wv = t >> 6;
  const int lane = t & 63;
  const int qd = lane >> 4, ln = lane & 15;
  const long row0 = (long)blockIdx.x * 128, col0 = (long)blockIdx.y * 128;
  const int wm = (wv >> 1) * 64, wn = (wv & 1) * 64;

  f32x4 acc[4][4];
#pragma unroll
  for (int i = 0; i < 4; i++)
#pragma unroll
    for (int j = 0; j < 4; j++) acc[i][j] = (f32x4){0.f, 0.f, 0.f, 0.f};

  const ushort* gA = A + (row0 + (t >> 2)) * (long)K + (t & 3) * 8;
  const ushort* gB = Bw + (col0 + (t >> 2)) * (long)K + (t & 3) * 8;
  ushort* lA = &As[wv * 512];
  ushort* lB = &Bs[wv * 512];
  const long K64 = 64l * K;

  for (int kt = 0; kt < K; kt += 32) {
    __syncthreads();
    gload_lds16(gA + kt,        lA);
    gload_lds16(gA + kt + K64,  lA + 2048);
    gload_lds16(gB + kt,        lB);
    gload_lds16(gB + kt + K64,  lB + 2048);
    __syncthreads();
    bf16x8 af[4], bf[4];
#pragma unroll
    for (int mi = 0; mi < 4; mi++)
      af[mi] = *(const bf16x8*)&As[(wm + mi * 16 + ln) * 32 + qd * 8];
#pragma unroll
    for (int ni = 0; ni < 4; ni++)
      bf[ni] = *(const bf16x8*)&Bs[(wn + ni * 16 + ln) * 32 + qd * 8];
#pragma unroll
    for (int mi = 0; mi < 4; mi++)
#pragma unroll
      for (int ni = 0; ni < 4; ni++)
        acc[mi][ni] = __builtin_amdgcn_mfma_f32_16x16x32_bf16(af[mi], bf[ni], acc[mi][ni], 0, 0, 0);
  }

  float bv[4];
#pragma unroll
  for (int ni = 0; ni < 4; ni++) bv[ni] = bias[col0 + wn + ni * 16 + ln];

  if (col0 >= vsplit) {
#pragma unroll
    for (int mi = 0; mi < 4; mi++)
#pragma unroll
      for (int ni = 0; ni < 4; ni++)
#pragma unroll
        for (int r = 0; r < 4; r++) {
          long row = row0 + wm + mi * 16 + qd * 4 + r;
          long col = col0 + wn + ni * 16 + ln - vsplit;
          vt[col * 4096 + row] = f2bf(acc[mi][ni][r] + bv[ni]);
        }
  } else {
#pragma unroll
    for (int mi = 0; mi < 4; mi++)
#pragma unroll
      for (int ni = 0; ni < 4; ni++)
#pragma unroll
        for (int r = 0; r < 4; r++) {
          long row = row0 + wm + mi * 16 + qd * 4 + r;
          long col = col0 + wn + ni * 16 + ln;
          float v = acc[mi][ni][r] + bv[ni];
          if (BF16OUT) ((ushort*)Cout)[row * ldc + col] = f2bf(v);
          else         ((float*)Cout)[row * ldc + col] = v;
        }
  }
}

// ---------------------------------------------------------------- RoPE in place on Q/K (qk buffer, ld=2560)
__global__ __launch_bounds__(256) void rope_kernel(ushort* __restrict__ qk)
{
  const int i = blockIdx.x * 256 + threadIdx.x;
  if (i >= 5242880) return;
  const int pair = i & 63;
  const int head = (i >> 6) % 20;
  const int row  = (i >> 6) / 20;
  const int pos  = row & 2047;
  const int base = head < 16 ? head * 128 : 2048 + (head - 16) * 128;
  ushort* p = qk + (long)row * 2560 + base + pair;
  const float v0 = bf2f(p[0]);
  const float v1 = bf2f(p[64]);
  const float inv = expf((float)pair * -0.14391156831212787f);
  const float ang = (float)pos * inv;
  const float sc = (head < 16) ? 0.08838834764831845f : 1.0f;  // fold 1/sqrt(d) into Q
  const float c = cosf(ang) * sc, s = sinf(ang) * sc;
  p[0]  = f2bf(v0 * c - v1 * s);
  p[64] = f2bf(v1 * c + v0 * s);
}

// ---------------------------------------------------------------- flash attention v5
// v4 structure (S^T = K·Q^T, O^T = V^T·P^T, 32x32x16 MFMA, m=0 softmax, kpos-phased),
// with ALL hot-loop unions removed (they were unpromoted allocas -> ~274 MB/launch of
// scratch traffic in v3/v4). P-frag now built as u32x4 insertelements + __builtin_bit_cast.
__global__ __launch_bounds__(256, 2) void flash_kernel(
    const ushort* __restrict__ qk, const ushort* __restrict__ vt,
    ushort* __restrict__ ctx)
{
  __shared__ ushort smem[17920];          // Ks [64][136] @0 (8704) + Vts [128][72] @8704 (9216)
  ushort* Ks  = smem;                     // reused as O-transpose buffer [128][136] at the end
  ushort* Vts = smem + 8704;

  const int t = threadIdx.x, lane = t & 63, wv = t >> 6;
  const int h2 = lane >> 5, m = lane & 31;
  const int q0 = blockIdx.x * 128;
  const int b = blockIdx.y >> 4, h = blockIdx.y & 15;
  const long rb = (long)b * 2048;
  const ushort* Qg  = qk + (rb + q0) * 2560 + h * 128;
  const ushort* Kg  = qk + rb * 2560 + 2048 + (h >> 2) * 128;
  const ushort* Vtg = vt + ((long)(h >> 2) * 128) * 4096 + rb;

  // Q B-frags in registers: lane (h2, m) holds Q[q = wv*32+m][d = 16*s2 + 8*h2 + 0..7]
  bf16x8 qf[8];
  {
    const ushort* qrow = Qg + (long)(wv * 32 + m) * 2560 + h2 * 8;
#pragma unroll
    for (int s2 = 0; s2 < 8; s2++)
      qf[s2] = *(const bf16x8*)(qrow + s2 * 16);
  }

  f32x16 oacc[4];
#pragma unroll
  for (int d = 0; d < 4; d++)
#pragma unroll
    for (int r = 0; r < 16; r++) oacc[d][r] = 0.f;
  float l_run = 0.f;

  const int sr  = t >> 4;          // 0..15 (K rows)
  const int sc8 = (t & 15) * 8;
  const int vd  = t >> 1;          // 0..127 (V d-rows)
  const int vc  = (t & 1) * 4;

  // prefetch tile kt=0
  uint4 kreg[4], vreg[4];
#pragma unroll
  for (int i = 0; i < 4; i++)
    kreg[i] = *(const uint4*)(Kg + (long)(16 * i + sr) * 2560 + sc8);
#pragma unroll
  for (int c = 0; c < 4; c++)
    vreg[c] = *(const uint4*)(Vtg + (long)vd * 4096 + (vc + c) * 8);

  for (int kt = 0; kt < 2048; kt += 64) {
    __syncthreads();                       // previous iter's LDS reads done
#pragma unroll
    for (int i = 0; i < 4; i++)
      *(uint4*)&Ks[(16 * i + sr) * 136 + sc8] = kreg[i];
#pragma unroll
    for (int c = 0; c < 4; c++)
      *(uint4*)&Vts[vd * 72 + (vc + c) * 8] = vreg[c];
    {
      int ktn = (kt + 64) & 2047;          // next tile loads stay in flight across compute
#pragma unroll
      for (int i = 0; i < 4; i++)
        kreg[i] = *(const uint4*)(Kg + (long)(ktn + 16 * i + sr) * 2560 + sc8);
#pragma unroll
      for (int c = 0; c < 4; c++)
        vreg[c] = *(const uint4*)(Vtg + (long)vd * 4096 + ktn + (vc + c) * 8);
    }
    __syncthreads();

    float s_sum = 0.f;
#pragma unroll
    for (int kb = 0; kb < 2; kb++) {
      // S^T[kpos-block kb][q-block wv] = K·Q^T  (16 live sacc regs)
      f32x16 sacc;
#pragma unroll
      for (int r = 0; r < 16; r++) sacc[r] = 0.f;
#pragma unroll
      for (int s2 = 0; s2 < 8; s2++) {
        bf16x8 kf = *(const bf16x8*)&Ks[(32 * kb + m) * 136 + s2 * 16 + h2 * 8];
        sacc = __builtin_amdgcn_mfma_f32_32x32x16_bf16(kf, qf[s2], sacc, 0, 0, 0);
      }
      // softmax (m=0) + build P^T B-frag + PV, one 16-k step at a time
#pragma unroll
      for (int sh = 0; sh < 2; sh++) {
        float e0 = __expf(sacc[8 * sh + 0]);
        float e1 = __expf(sacc[8 * sh + 1]);
        float e2 = __expf(sacc[8 * sh + 2]);
        float e3 = __expf(sacc[8 * sh + 3]);
        float e4 = __expf(sacc[8 * sh + 4]);
        float e5 = __expf(sacc[8 * sh + 5]);
        float e6 = __expf(sacc[8 * sh + 6]);
        float e7 = __expf(sacc[8 * sh + 7]);
        s_sum += ((e0 + e1) + (e2 + e3)) + ((e4 + e5) + (e6 + e7));
        unsigned u0 = pk2bf(e0, e1);
        unsigned u1 = pk2bf(e2, e3);
        unsigned u2 = pk2bf(e4, e5);
        unsigned u3 = pk2bf(e6, e7);
        unsigned u0s = (unsigned)__shfl_xor((int)u0, 32, 64);
        unsigned u1s = (unsigned)__shfl_xor((int)u1, 32, 64);
        unsigned u2s = (unsigned)__shfl_xor((int)u2, 32, 64);
        unsigned u3s = (unsigned)__shfl_xor((int)u3, 32, 64);
        u32x4 pu;
        pu.x = h2 ? u2s : u0;
        pu.y = h2 ? u3s : u1;
        pu.z = h2 ? u2 : u0s;
        pu.w = h2 ? u3 : u1s;
        bf16x8 pfv = __builtin_bit_cast(bf16x8, pu);
        const int s = 2 * kb + sh;
#pragma unroll
        for (int db = 0; db < 4; db++) {
          bf16x8 vf = *(const bf16x8*)&Vts[(db * 32 + m) * 72 + s * 16 + h2 * 8];
          oacc[db] = __builtin_amdgcn_mfma_f32_32x32x16_bf16(vf, pfv, oacc[db], 0, 0, 0);
        }
      }
    }
    l_run += s_sum + __int_as_float(__shfl_xor(__float_as_int(s_sum), 32, 64));
  }

  // epilogue: O^T/l -> LDS transpose -> coalesced ctx stores
  const float linv = 1.f / (l_run + 1e-10f);
  __syncthreads();                          // all waves done reading Ks/Vts
  ushort* Obuf = smem;                      // [128 q][136]
#pragma unroll
  for (int db = 0; db < 4; db++)
#pragma unroll
    for (int r = 0; r < 16; r++) {
      int d = db * 32 + (r & 3) + 8 * (r >> 2) + 4 * h2;
      Obuf[(wv * 32 + m) * 136 + d] = f2bf(oacc[db][r] * linv);
    }
  __syncthreads();
  {
    int qr = t >> 1;
    ushort* dst = ctx + (rb + q0 + qr) * 2048 + h * 128;
#pragma unroll
    for (int c = 0; c < 8; c++) {
      int off = ((t & 1) * 8 + c) * 8;
      *(uint4*)(dst + off) = *(const uint4*)&Obuf[qr * 136 + off];
    }
  }
}

// ---------------------------------------------------------------- launch
extern "C" void kernel_launch(void* const* d_in, const int* in_sizes, int n_in,
                              void* d_out, int out_size, void* d_ws, size_t ws_size,
                              hipStream_t stream)
{
  const float* hs = (const float*)d_in[0];
  const float* qw = (const float*)d_in[1];
  const float* qb = (const float*)d_in[2];
  const float* kw = (const float*)d_in[3];
  const float* kb = (const float*)d_in[4];
  const float* vw = (const float*)d_in[5];
  const float* vb = (const float*)d_in[6];
  const float* ow = (const float*)d_in[7];
  const float* ob = (const float*)d_in[8];

  char* ws = (char*)d_ws;
  ushort* hs_b   = (ushort*)(ws);                 // 16,777,216 B
  ushort* qkvw_b = (ushort*)(ws + 16777216);      // 12,582,912 B
  ushort* ow_b   = (ushort*)(ws + 29360128);      //  8,388,608 B
  float*  qkvb   = (float*) (ws + 37748736);      //     12,288 B
  ushort* qkbuf  = (ushort*)(ws + 37761024);      // 20,971,520 B  [4096][2560]
  ushort* vtbuf  = (ushort*)(ws + 58732544);      //  4,194,304 B  [512][4096]
  ushort* ctx    = (ushort*)(ws + 62926848);      // 16,777,216 B

  prep_kernel<<<1024, 256, 0, stream>>>(hs, qw, kw, vw, ow, qb, kb, vb,
                                        hs_b, qkvw_b, ow_b, qkvb);
  gemm_bt<1><<<dim3(32, 24), 256, 0, stream>>>(hs_b, qkvw_b, qkvb, qkbuf, vtbuf,
                                               4096, 3072, 2048, 2560, 2560);
  rope_kernel<<<20480, 256, 0, stream>>>(qkbuf);
  flash_kernel<<<dim3(16, 32), 256, 0, stream>>>(qkbuf, vtbuf, ctx);
  gemm_bt<0><<<dim3(32, 16), 256, 0, stream>>>(ctx, ow_b, ob, d_out, nullptr,
                                               4096, 2048, 2048, 2048, 1 << 30);
}

// Round 6
// 335.997 us; speedup vs baseline: 1.3445x; 1.3404x over previous
//
#include <hip/hip_runtime.h>
#include <hip/hip_bf16.h>
#include <math.h>

typedef __attribute__((ext_vector_type(8))) short bf16x8;
typedef __attribute__((ext_vector_type(4))) float f32x4;
typedef __attribute__((ext_vector_type(16))) float f32x16;
typedef __attribute__((ext_vector_type(4))) unsigned int u32x4;

__device__ __forceinline__ ushort f2bf(float f) {
  unsigned u = __float_as_uint(f);
  u = u + 0x7FFFu + ((u >> 16) & 1u);
  return (ushort)(u >> 16);
}
__device__ __forceinline__ float bf2f(ushort h) {
  return __uint_as_float(((unsigned)h) << 16);
}
__device__ __forceinline__ unsigned pk2bf(float a, float b) {
  unsigned ua = __float_as_uint(a);
  unsigned ub = __float_as_uint(b);
  ua = ua + 0x7FFFu + ((ua >> 16) & 1u);
  ub = ub + 0x7FFFu + ((ub >> 16) & 1u);
  return (ua >> 16) | (ub & 0xFFFF0000u);
}
__device__ __forceinline__ void gload_lds16(const ushort* g, ushort* l) {
  __builtin_amdgcn_global_load_lds((const __attribute__((address_space(1))) void*)g,
                                   (__attribute__((address_space(3))) void*)l, 16, 0, 0);
}

// ---------------------------------------------------------------- prep: casts + packing
__global__ __launch_bounds__(256) void prep_kernel(
    const float* __restrict__ hs, const float* __restrict__ qw,
    const float* __restrict__ kw, const float* __restrict__ vw,
    const float* __restrict__ ow, const float* __restrict__ qb,
    const float* __restrict__ kb, const float* __restrict__ vb,
    ushort* __restrict__ hs_b, ushort* __restrict__ qkvw_b,
    ushort* __restrict__ ow_b, float* __restrict__ qkvb)
{
  const int idx = blockIdx.x * 256 + threadIdx.x;
  const int stride = gridDim.x * 256;
  const float4* hs4 = (const float4*)hs;
  const float4* qw4 = (const float4*)qw;
  const float4* kw4 = (const float4*)kw;
  const float4* vw4 = (const float4*)vw;
  const float4* ow4 = (const float4*)ow;
  ushort4* hsb4 = (ushort4*)hs_b;
  ushort4* qkvwb4 = (ushort4*)qkvw_b;
  ushort4* owb4 = (ushort4*)ow_b;

  for (int i = idx; i < 2097152; i += stride) {
    float4 v = hs4[i];
    ushort4 o; o.x=f2bf(v.x); o.y=f2bf(v.y); o.z=f2bf(v.z); o.w=f2bf(v.w);
    hsb4[i] = o;
  }
  for (int i = idx; i < 1048576; i += stride) {
    float4 v = qw4[i];
    ushort4 o; o.x=f2bf(v.x); o.y=f2bf(v.y); o.z=f2bf(v.z); o.w=f2bf(v.w);
    qkvwb4[i] = o;
  }
  for (int i = idx; i < 262144; i += stride) {
    float4 v = kw4[i];
    ushort4 o; o.x=f2bf(v.x); o.y=f2bf(v.y); o.z=f2bf(v.z); o.w=f2bf(v.w);
    qkvwb4[1048576 + i] = o;
  }
  for (int i = idx; i < 262144; i += stride) {
    float4 v = vw4[i];
    ushort4 o; o.x=f2bf(v.x); o.y=f2bf(v.y); o.z=f2bf(v.z); o.w=f2bf(v.w);
    qkvwb4[1310720 + i] = o;
  }
  for (int i = idx; i < 1048576; i += stride) {
    float4 v = ow4[i];
    ushort4 o; o.x=f2bf(v.x); o.y=f2bf(v.y); o.z=f2bf(v.z); o.w=f2bf(v.w);
    owb4[i] = o;
  }
  for (int i = idx; i < 3072; i += stride)
    qkvb[i] = (i < 2048) ? qb[i] : (i < 2560 ? kb[i - 2048] : vb[i - 2560]);
}

// ---------------------------------------------------------------- GEMM: C = A(MxK) * Bw(NxK)^T + bias
template<int BF16OUT>
__global__ __launch_bounds__(256) void gemm_bt(
    const ushort* __restrict__ A, const ushort* __restrict__ Bw,
    const float* __restrict__ bias, void* __restrict__ Cout,
    ushort* __restrict__ vt,
    int M, int N, int K, int ldc, int vsplit)
{
  __shared__ ushort As[128 * 32];
  __shared__ ushort Bs[128 * 32];
  const int t = threadIdx.x;
  const int wv = t >> 6;
  const int lane = t & 63;
  const int qd = lane >> 4, ln = lane & 15;
  const long row0 = (long)blockIdx.x * 128, col0 = (long)blockIdx.y * 128;
  const int wm = (wv >> 1) * 64, wn = (wv & 1) * 64;

  f32x4 acc[4][4];
#pragma unroll
  for (int i = 0; i < 4; i++)
#pragma unroll
    for (int j = 0; j < 4; j++) acc[i][j] = (f32x4){0.f, 0.f, 0.f, 0.f};

  const ushort* gA = A + (row0 + (t >> 2)) * (long)K + (t & 3) * 8;
  const ushort* gB = Bw + (col0 + (t >> 2)) * (long)K + (t & 3) * 8;
  ushort* lA = &As[wv * 512];
  ushort* lB = &Bs[wv * 512];
  const long K64 = 64l * K;

  for (int kt = 0; kt < K; kt += 32) {
    __syncthreads();
    gload_lds16(gA + kt,        lA);
    gload_lds16(gA + kt + K64,  lA + 2048);
    gload_lds16(gB + kt,        lB);
    gload_lds16(gB + kt + K64,  lB + 2048);
    __syncthreads();
    bf16x8 af[4], bf[4];
#pragma unroll
    for (int mi = 0; mi < 4; mi++)
      af[mi] = *(const bf16x8*)&As[(wm + mi * 16 + ln) * 32 + qd * 8];
#pragma unroll
    for (int ni = 0; ni < 4; ni++)
      bf[ni] = *(const bf16x8*)&Bs[(wn + ni * 16 + ln) * 32 + qd * 8];
#pragma unroll
    for (int mi = 0; mi < 4; mi++)
#pragma unroll
      for (int ni = 0; ni < 4; ni++)
        acc[mi][ni] = __builtin_amdgcn_mfma_f32_16x16x32_bf16(af[mi], bf[ni], acc[mi][ni], 0, 0, 0);
  }

  float bv[4];
#pragma unroll
  for (int ni = 0; ni < 4; ni++) bv[ni] = bias[col0 + wn + ni * 16 + ln];

  if (col0 >= vsplit) {
#pragma unroll
    for (int mi = 0; mi < 4; mi++)
#pragma unroll
      for (int ni = 0; ni < 4; ni++)
#pragma unroll
        for (int r = 0; r < 4; r++) {
          long row = row0 + wm + mi * 16 + qd * 4 + r;
          long col = col0 + wn + ni * 16 + ln - vsplit;
          vt[col * 4096 + row] = f2bf(acc[mi][ni][r] + bv[ni]);
        }
  } else {
#pragma unroll
    for (int mi = 0; mi < 4; mi++)
#pragma unroll
      for (int ni = 0; ni < 4; ni++)
#pragma unroll
        for (int r = 0; r < 4; r++) {
          long row = row0 + wm + mi * 16 + qd * 4 + r;
          long col = col0 + wn + ni * 16 + ln;
          float v = acc[mi][ni][r] + bv[ni];
          if (BF16OUT) ((ushort*)Cout)[row * ldc + col] = f2bf(v);
          else         ((float*)Cout)[row * ldc + col] = v;
        }
  }
}

// ---------------------------------------------------------------- RoPE in place on Q/K (qk buffer, ld=2560)
__global__ __launch_bounds__(256) void rope_kernel(ushort* __restrict__ qk)
{
  const int i = blockIdx.x * 256 + threadIdx.x;
  if (i >= 5242880) return;
  const int pair = i & 63;
  const int head = (i >> 6) % 20;
  const int row  = (i >> 6) / 20;
  const int pos  = row & 2047;
  const int base = head < 16 ? head * 128 : 2048 + (head - 16) * 128;
  ushort* p = qk + (long)row * 2560 + base + pair;
  const float v0 = bf2f(p[0]);
  const float v1 = bf2f(p[64]);
  const float inv = expf((float)pair * -0.14391156831212787f);
  const float ang = (float)pos * inv;
  const float sc = (head < 16) ? 0.08838834764831845f : 1.0f;  // fold 1/sqrt(d) into Q
  const float c = cosf(ang) * sc, s = sinf(ang) * sc;
  p[0]  = f2bf(v0 * c - v1 * s);
  p[64] = f2bf(v1 * c + v0 * s);
}

// ---------------------------------------------------------------- flash attention v6
// v5 math (S^T = K·Q^T, O^T = V^T·P^T, 32x32x16, m=0 softmax, kpos-phased), staging
// rebuilt: async global_load_lds (zero staging VGPRs — v3..v5 spilled the register
// prefetch, ~270 MB/launch scratch writes) + LDS double-buffer (issue tile i+1 after
// the barrier, compute tile i — loads in flight across compute). No LDS padding
// (DMA dest is lane*16-contiguous); bank spread via XOR-chunk swizzle on the
// GLOBAL address side: K chunk' = c ^ (row&15), V chunk' = c ^ (row&7) ->
// per-8-lane-phase banks 4*((c^m)&7) all distinct -> conflict-free b128 reads.
__global__ __launch_bounds__(256, 2) void flash_kernel(
    const ushort* __restrict__ qk, const ushort* __restrict__ vt,
    ushort* __restrict__ ctx)
{
  __shared__ ushort smem[32768];  // buf0: Ks[64][128]@0, Vts[128][64]@8192; buf1 @16384
  const int t = threadIdx.x, lane = t & 63, wv = t >> 6;
  const int h2 = lane >> 5, m = lane & 31;
  const int q0 = blockIdx.x * 128;
  const int b = blockIdx.y >> 4, h = blockIdx.y & 15;
  const long rb = (long)b * 2048;
  const ushort* Qg  = qk + (rb + q0) * 2560 + h * 128;
  const ushort* Kg  = qk + rb * 2560 + 2048 + (h >> 2) * 128;
  const ushort* Vtg = vt + ((long)(h >> 2) * 128) * 4096 + rb;

  // Q B-frags in registers: lane (h2, m) holds Q[q = wv*32+m][d = 16*s2 + 8*h2 + 0..7]
  bf16x8 qf[8];
  {
    const ushort* qrow = Qg + (long)(wv * 32 + m) * 2560 + h2 * 8;
#pragma unroll
    for (int s2 = 0; s2 < 8; s2++)
      qf[s2] = *(const bf16x8*)(qrow + s2 * 16);
  }

  f32x16 oacc[4];
#pragma unroll
  for (int d = 0; d < 4; d++)
#pragma unroll
    for (int r = 0; r < 16; r++) oacc[d][r] = 0.f;
  float l_run = 0.f;

  // per-lane global staging addresses (tile 0), swizzled chunk on global side
  const ushort* gK[4];
  const ushort* gV[4];
#pragma unroll
  for (int s = 0; s < 4; s++) {
    int krow = wv * 16 + s * 4 + (lane >> 4);              // 0..63
    int kcd  = (lane & 15) ^ (krow & 15);
    gK[s] = Kg + (long)krow * 2560 + kcd * 8;
    int vrow = wv * 32 + s * 8 + (lane >> 3);              // 0..127
    int vcd  = (lane & 7) ^ ((lane >> 3) & 7);
    gV[s] = Vtg + (long)vrow * 4096 + vcd * 8;
  }
  const int ldsK = wv * 16 * 128;                          // + s*4*128
  const int ldsV = 8192 + wv * 32 * 64;                    // + s*8*64

  // preload tile 0 -> buf 0, advance pointers to tile 1
#pragma unroll
  for (int s = 0; s < 4; s++) gload_lds16(gK[s], smem + ldsK + s * 512);
#pragma unroll
  for (int s = 0; s < 4; s++) gload_lds16(gV[s], smem + ldsV + s * 512);
#pragma unroll
  for (int s = 0; s < 4; s++) { gK[s] += 64l * 2560; gV[s] += 64; }

  const int mk = (m & 15) ;   // K swizzle key
  const int mv = (m & 7);     // V swizzle key

  for (int kt = 0; kt < 2048; kt += 64) {
    const int cb = (kt >> 6) & 1;
    __syncthreads();   // drains DMA for this tile; prev tile's LDS reads done
    if (kt < 1984) {   // issue tile i+1 into the other buffer (in flight across compute)
      ushort* nb = smem + (cb ^ 1) * 16384;
#pragma unroll
      for (int s = 0; s < 4; s++) gload_lds16(gK[s], nb + ldsK + s * 512);
#pragma unroll
      for (int s = 0; s < 4; s++) gload_lds16(gV[s], nb + ldsV + s * 512);
#pragma unroll
      for (int s = 0; s < 4; s++) { gK[s] += 64l * 2560; gV[s] += 64; }
    }
    const ushort* KsB  = smem + cb * 16384;
    const ushort* VtsB = KsB + 8192;

    float s_sum = 0.f;
#pragma unroll
    for (int kb = 0; kb < 2; kb++) {
      f32x16 sacc;
#pragma unroll
      for (int r = 0; r < 16; r++) sacc[r] = 0.f;
#pragma unroll
      for (int s2 = 0; s2 < 8; s2++) {
        bf16x8 kf = *(const bf16x8*)&KsB[(32 * kb + m) * 128 + ((s2 * 2 + h2) ^ mk) * 8];
        sacc = __builtin_amdgcn_mfma_f32_32x32x16_bf16(kf, qf[s2], sacc, 0, 0, 0);
      }
#pragma unroll
      for (int sh = 0; sh < 2; sh++) {
        float e0 = __expf(sacc[8 * sh + 0]);
        float e1 = __expf(sacc[8 * sh + 1]);
        float e2 = __expf(sacc[8 * sh + 2]);
        float e3 = __expf(sacc[8 * sh + 3]);
        float e4 = __expf(sacc[8 * sh + 4]);
        float e5 = __expf(sacc[8 * sh + 5]);
        float e6 = __expf(sacc[8 * sh + 6]);
        float e7 = __expf(sacc[8 * sh + 7]);
        s_sum += ((e0 + e1) + (e2 + e3)) + ((e4 + e5) + (e6 + e7));
        unsigned u0 = pk2bf(e0, e1);
        unsigned u1 = pk2bf(e2, e3);
        unsigned u2 = pk2bf(e4, e5);
        unsigned u3 = pk2bf(e6, e7);
        unsigned u0s = (unsigned)__shfl_xor((int)u0, 32, 64);
        unsigned u1s = (unsigned)__shfl_xor((int)u1, 32, 64);
        unsigned u2s = (unsigned)__shfl_xor((int)u2, 32, 64);
        unsigned u3s = (unsigned)__shfl_xor((int)u3, 32, 64);
        u32x4 pu;
        pu.x = h2 ? u2s : u0;
        pu.y = h2 ? u3s : u1;
        pu.z = h2 ? u2 : u0s;
        pu.w = h2 ? u3 : u1s;
        bf16x8 pfv = __builtin_bit_cast(bf16x8, pu);
        const int s = 2 * kb + sh;
#pragma unroll
        for (int db = 0; db < 4; db++) {
          bf16x8 vf = *(const bf16x8*)&VtsB[(db * 32 + m) * 64 + ((s * 2 + h2) ^ mv) * 8];
          oacc[db] = __builtin_amdgcn_mfma_f32_32x32x16_bf16(vf, pfv, oacc[db], 0, 0, 0);
        }
      }
    }
    l_run += s_sum + __int_as_float(__shfl_xor(__float_as_int(s_sum), 32, 64));
  }

  // epilogue: O^T/l -> LDS transpose -> coalesced ctx stores
  const float linv = 1.f / (l_run + 1e-10f);
  __syncthreads();                          // all waves done with staging buffers
  ushort* Obuf = smem;                      // [128 q][136]
#pragma unroll
  for (int db = 0; db < 4; db++)
#pragma unroll
    for (int r = 0; r < 16; r++) {
      int d = db * 32 + (r & 3) + 8 * (r >> 2) + 4 * h2;
      Obuf[(wv * 32 + m) * 136 + d] = f2bf(oacc[db][r] * linv);
    }
  __syncthreads();
  {
    int qr = t >> 1;
    ushort* dst = ctx + (rb + q0 + qr) * 2048 + h * 128;
#pragma unroll
    for (int c = 0; c < 8; c++) {
      int off = ((t & 1) * 8 + c) * 8;
      *(uint4*)(dst + off) = *(const uint4*)&Obuf[qr * 136 + off];
    }
  }
}

// ---------------------------------------------------------------- launch
extern "C" void kernel_launch(void* const* d_in, const int* in_sizes, int n_in,
                              void* d_out, int out_size, void* d_ws, size_t ws_size,
                              hipStream_t stream)
{
  const float* hs = (const float*)d_in[0];
  const float* qw = (const float*)d_in[1];
  const float* qb = (const float*)d_in[2];
  const float* kw = (const float*)d_in[3];
  const float* kb = (const float*)d_in[4];
  const float* vw = (const float*)d_in[5];
  const float* vb = (const float*)d_in[6];
  const float* ow = (const float*)d_in[7];
  const float* ob = (const float*)d_in[8];

  char* ws = (char*)d_ws;
  ushort* hs_b   = (ushort*)(ws);                 // 16,777,216 B
  ushort* qkvw_b = (ushort*)(ws + 16777216);      // 12,582,912 B
  ushort* ow_b   = (ushort*)(ws + 29360128);      //  8,388,608 B
  float*  qkvb   = (float*) (ws + 37748736);      //     12,288 B
  ushort* qkbuf  = (ushort*)(ws + 37761024);      // 20,971,520 B  [4096][2560]
  ushort* vtbuf  = (ushort*)(ws + 58732544);      //  4,194,304 B  [512][4096]
  ushort* ctx    = (ushort*)(ws + 62926848);      // 16,777,216 B

  prep_kernel<<<1024, 256, 0, stream>>>(hs, qw, kw, vw, ow, qb, kb, vb,
                                        hs_b, qkvw_b, ow_b, qkvb);
  gemm_bt<1><<<dim3(32, 24), 256, 0, stream>>>(hs_b, qkvw_b, qkvb, qkbuf, vtbuf,
                                               4096, 3072, 2048, 2560, 2560);
  rope_kernel<<<20480, 256, 0, stream>>>(qkbuf);
  flash_kernel<<<dim3(16, 32), 256, 0, stream>>>(qkbuf, vtbuf, ctx);
  gemm_bt<0><<<dim3(32, 16), 256, 0, stream>>>(ctx, ow_b, ob, d_out, nullptr,
                                               4096, 2048, 2048, 2048, 1 << 30);
}